// Round 2
// baseline (572.657 us; speedup 1.0000x reference)
//
#include <hip/hip_runtime.h>
#include <cstdint>
#include <cstddef>

// Problem constants
#define DIMN 1024
#define SEQ  2048
#define NBAT 4
#define TOKS (NBAT * SEQ)   // 8192

typedef unsigned short u16;
typedef unsigned int   u32;

typedef __bf16 bf16x8 __attribute__((ext_vector_type(8)));
typedef float  f32x4  __attribute__((ext_vector_type(4)));

// ---- helpers ----------------------------------------------------------------

__device__ __forceinline__ u16 f2b(float f) {
  union { float f; u32 u; } v; v.f = f;
  u32 r = v.u + 0x7fffu + ((v.u >> 16) & 1u);   // round-to-nearest-even
  return (u16)(r >> 16);
}

__device__ __forceinline__ float gelu_exact(float v) {
  return 0.5f * v * (1.0f + erff(v * 0.70710678118654752f));
}

// block (256) reduction of two sums
__device__ __forceinline__ void blk_sum2(float& a, float& b, float* sm) {
  #pragma unroll
  for (int o = 32; o >= 1; o >>= 1) {
    a += __shfl_xor(a, o, 64);
    b += __shfl_xor(b, o, 64);
  }
  int w = threadIdx.x >> 6;
  if ((threadIdx.x & 63) == 0) { sm[w] = a; sm[4 + w] = b; }
  __syncthreads();
  a = sm[0] + sm[1] + sm[2] + sm[3];
  b = sm[4] + sm[5] + sm[6] + sm[7];
  __syncthreads();
}

__device__ __forceinline__ float blk_max(float a, float* sm) {
  #pragma unroll
  for (int o = 32; o >= 1; o >>= 1) a = fmaxf(a, __shfl_xor(a, o, 64));
  int w = threadIdx.x >> 6;
  if ((threadIdx.x & 63) == 0) sm[w] = a;
  __syncthreads();
  float r = fmaxf(fmaxf(sm[0], sm[1]), fmaxf(sm[2], sm[3]));
  __syncthreads();
  return r;
}

__device__ __forceinline__ float blk_sum1(float a, float* sm) {
  #pragma unroll
  for (int o = 32; o >= 1; o >>= 1) a += __shfl_xor(a, o, 64);
  int w = threadIdx.x >> 6;
  if ((threadIdx.x & 63) == 0) sm[w] = a;
  __syncthreads();
  float r = sm[0] + sm[1] + sm[2] + sm[3];
  __syncthreads();
  return r;
}

// ---- prep kernels -----------------------------------------------------------

// f32 -> bf16 elementwise, 4 elems/thread
__global__ __launch_bounds__(256) void conv_x(const float* __restrict__ x,
                                              u16* __restrict__ xb) {
  size_t i = ((size_t)blockIdx.x * 256 + threadIdx.x) * 4;
  float4 v = *(const float4*)(x + i);
  uint2 o;
  o.x = (u32)f2b(v.x) | ((u32)f2b(v.y) << 16);
  o.y = (u32)f2b(v.z) | ((u32)f2b(v.w) << 16);
  *(uint2*)(xb + i) = o;
}

// W [K][N] f32  ->  WT [N][K] bf16   (DIMN x DIMN)
__global__ __launch_bounds__(256) void transpose_w(const float* __restrict__ W,
                                                   u16* __restrict__ WT) {
  __shared__ float t[32][33];
  int tx = threadIdx.x, ty = threadIdx.y;
  int k0 = blockIdx.x * 32, n0 = blockIdx.y * 32;
  #pragma unroll
  for (int j = 0; j < 32; j += 8)
    t[ty + j][tx] = W[(size_t)(k0 + ty + j) * DIMN + n0 + tx];
  __syncthreads();
  #pragma unroll
  for (int j = 0; j < 32; j += 8)
    WT[(size_t)(n0 + ty + j) * DIMN + k0 + tx] = f2b(t[tx][ty + j]);
}

// ---- MFMA GEMM: C[M,N] = A[M,K] * B^T  (B given as [N][K]) ------------------
// 128x128 tile, BK=64, 256 threads = 4 waves, each wave 64x64 (4x4 of 16x16x32)
// EPI: 0 = store f32 (no bias)
//      1 = +bias, store bf16
//      2 = +bias, store bf16 transposed as VT[b][d][tok] (V projection)
//      4 = +bias, GELU, store bf16
//      5 = +bias, GELU, store f32
template <int EPI>
__global__ __launch_bounds__(256) void gemm_bt(
    const u16* __restrict__ A, const u16* __restrict__ Bm,
    float* __restrict__ Cf, u16* __restrict__ Cb,
    const float* __restrict__ bias,
    int M, int N, int K, int ldc)
{
  __shared__ u16 As[128 * 72];  // stride 72 (+8 pad): 144B rows = 9x16B, aligned
  __shared__ u16 Bs[128 * 72];

  const int tid  = threadIdx.x;
  const int bm0  = blockIdx.x * 128;
  const int bn0  = blockIdx.y * 128;
  const int wave = tid >> 6, lane = tid & 63;
  const int wm   = (wave >> 1) * 64, wn = (wave & 1) * 64;
  const int l16  = lane & 15, quad = lane >> 4;

  f32x4 acc[4][4] = {};

  for (int k0 = 0; k0 < K; k0 += 64) {
    // stage A-tile and B-tile: 128 rows x 64 bf16 each = 1024 16B-chunks each
    #pragma unroll
    for (int i = 0; i < 4; ++i) {
      int c   = tid + i * 256;
      int row = c >> 3;
      int col = (c & 7) * 8;
      *(uint4*)(&As[row * 72 + col]) =
          *(const uint4*)(A + (size_t)(bm0 + row) * K + k0 + col);
      *(uint4*)(&Bs[row * 72 + col]) =
          *(const uint4*)(Bm + (size_t)(bn0 + row) * K + k0 + col);
    }
    __syncthreads();

    #pragma unroll
    for (int kk = 0; kk < 64; kk += 32) {
      bf16x8 af[4], bfr[4];
      #pragma unroll
      for (int t = 0; t < 4; ++t)
        af[t] = *(const bf16x8*)(&As[(wm + t * 16 + l16) * 72 + kk + quad * 8]);
      #pragma unroll
      for (int t = 0; t < 4; ++t)
        bfr[t] = *(const bf16x8*)(&Bs[(wn + t * 16 + l16) * 72 + kk + quad * 8]);
      #pragma unroll
      for (int mt = 0; mt < 4; ++mt)
        #pragma unroll
        for (int nt = 0; nt < 4; ++nt)
          acc[mt][nt] = __builtin_amdgcn_mfma_f32_16x16x32_bf16(
              af[mt], bfr[nt], acc[mt][nt], 0, 0, 0);
    }
    __syncthreads();
  }

  // epilogue: C/D layout col = lane&15, row = quad*4 + reg
  #pragma unroll
  for (int mt = 0; mt < 4; ++mt) {
    int grow0 = bm0 + wm + mt * 16 + quad * 4;
    #pragma unroll
    for (int nt = 0; nt < 4; ++nt) {
      int gcol = bn0 + wn + nt * 16 + l16;
      float bv = (EPI != 0) ? bias[gcol] : 0.0f;
      #pragma unroll
      for (int r = 0; r < 4; ++r) {
        float v  = acc[mt][nt][r] + bv;
        int grow = grow0 + r;
        if (EPI == 0) {
          Cf[(size_t)grow * ldc + gcol] = v;
        } else if (EPI == 1) {
          Cb[(size_t)grow * ldc + gcol] = f2b(v);
        } else if (EPI == 2) {
          // VT[b][d][tok]: b = grow>>11, tok = grow&2047, d = gcol
          Cb[(size_t)((grow >> 11) * DIMN + gcol) * SEQ + (grow & 2047)] = f2b(v);
        } else if (EPI == 4) {
          Cb[(size_t)grow * ldc + gcol] = f2b(gelu_exact(v));
        } else {  // 5
          Cf[(size_t)grow * ldc + gcol] = gelu_exact(v);
        }
      }
    }
  }
}

// ---- softmax over rows of 2048, scale 1/8 folded in, write bf16 P -----------
__global__ __launch_bounds__(256) void softmax_rows(const float* __restrict__ Sc,
                                                    u16* __restrict__ P) {
  __shared__ float sm[8];
  int row = blockIdx.x, t = threadIdx.x;
  const float* s = Sc + (size_t)row * SEQ;
  float v[8];
  float mx = -1e30f;
  #pragma unroll
  for (int i = 0; i < 8; ++i) {
    v[i] = s[t + i * 256] * 0.125f;
    mx = fmaxf(mx, v[i]);
  }
  mx = blk_max(mx, sm);
  float sum = 0.0f;
  #pragma unroll
  for (int i = 0; i < 8; ++i) { v[i] = __expf(v[i] - mx); sum += v[i]; }
  sum = blk_sum1(sum, sm);
  float inv = 1.0f / sum;
  u16* p = P + (size_t)row * SEQ;
  #pragma unroll
  for (int i = 0; i < 8; ++i) p[t + i * 256] = f2b(v[i] * inv);
}

// ---- LN(attn + x)*g_at+b_at -> at; LN(at + x)*g_ln+b_ln -> h (f32 + bf16) ---
__global__ __launch_bounds__(256) void ln1_fused(
    const float* __restrict__ attn, const float* __restrict__ x,
    const float* __restrict__ g_at, const float* __restrict__ b_at,
    const float* __restrict__ g_ln, const float* __restrict__ b_ln,
    float* __restrict__ hres, u16* __restrict__ hb)
{
  __shared__ float sm[8];
  int row = blockIdx.x, t = threadIdx.x;
  size_t base = (size_t)row * DIMN;
  float y[4], xr[4];
  float s = 0.0f, s2 = 0.0f;
  #pragma unroll
  for (int i = 0; i < 4; ++i) {
    int c = t + i * 256;
    xr[i] = x[base + c];
    y[i]  = attn[base + c] + xr[i];
    s += y[i]; s2 += y[i] * y[i];
  }
  blk_sum2(s, s2, sm);
  float m  = s * (1.0f / DIMN);
  float rs = rsqrtf(s2 * (1.0f / DIMN) - m * m + 1e-5f);
  float z[4];
  s = 0.0f; s2 = 0.0f;
  #pragma unroll
  for (int i = 0; i < 4; ++i) {
    int c = t + i * 256;
    float at = (y[i] - m) * rs * g_at[c] + b_at[c];
    z[i] = at + xr[i];
    s += z[i]; s2 += z[i] * z[i];
  }
  blk_sum2(s, s2, sm);
  float m2  = s * (1.0f / DIMN);
  float rs2 = rsqrtf(s2 * (1.0f / DIMN) - m2 * m2 + 1e-5f);
  #pragma unroll
  for (int i = 0; i < 4; ++i) {
    int c = t + i * 256;
    float h = (z[i] - m2) * rs2 * g_ln[c] + b_ln[c];
    hres[base + c] = h;
    hb[base + c]   = f2b(h);
  }
}

// ---- out = LN(u + hres)*g_ln + b_ln ----------------------------------------
__global__ __launch_bounds__(256) void ln2_final(
    const float* __restrict__ u, const float* __restrict__ hres,
    const float* __restrict__ g, const float* __restrict__ bb,
    float* __restrict__ out)
{
  __shared__ float sm[8];
  int row = blockIdx.x, t = threadIdx.x;
  size_t base = (size_t)row * DIMN;
  float y[4];
  float s = 0.0f, s2 = 0.0f;
  #pragma unroll
  for (int i = 0; i < 4; ++i) {
    int c = t + i * 256;
    y[i] = u[base + c] + hres[base + c];
    s += y[i]; s2 += y[i] * y[i];
  }
  blk_sum2(s, s2, sm);
  float m  = s * (1.0f / DIMN);
  float rs = rsqrtf(s2 * (1.0f / DIMN) - m * m + 1e-5f);
  #pragma unroll
  for (int i = 0; i < 4; ++i) {
    int c = t + i * 256;
    out[base + c] = (y[i] - m) * rs * g[c] + bb[c];
  }
}

// ---- launch -----------------------------------------------------------------

extern "C" void kernel_launch(void* const* d_in, const int* in_sizes, int n_in,
                              void* d_out, int out_size, void* d_ws, size_t ws_size,
                              hipStream_t stream)
{
  const float* x    = (const float*)d_in[0];
  const float* Wq   = (const float*)d_in[1];
  const float* bq   = (const float*)d_in[2];
  const float* Wk   = (const float*)d_in[3];
  const float* bk   = (const float*)d_in[4];
  const float* Wv   = (const float*)d_in[5];
  const float* bv   = (const float*)d_in[6];
  const float* g_at = (const float*)d_in[7];
  const float* b_at = (const float*)d_in[8];
  const float* g_ln = (const float*)d_in[9];
  const float* b_ln = (const float*)d_in[10];
  const float* W1   = (const float*)d_in[11];
  const float* c1   = (const float*)d_in[12];
  const float* W2   = (const float*)d_in[13];
  const float* c2   = (const float*)d_in[14];
  float* out = (float*)d_out;

  // workspace layout (1 MiB units). Peak: 146 MiB.
  //   0..16   xb (bf16 x)        -> aliased by Sc during attention
  //  16..18   W1T   18..20 W2T   20..22 WqT  22..24 WkT  24..26 WvT
  //  26..42   Qb                 -> aliased by hb after attention
  //  42..58   Kb                 -> aliased by tb after attention
  //  58..74   VT
  //  74..82   Pb
  //  82..114  attn f32           -> reused as u (FFN output)
  // 114..146  hres f32
  char* ws = (char*)d_ws;
  const size_t MB = 1u << 20;
  u16*   xb   = (u16*)  (ws + 0 * MB);
  u16*   W1T  = (u16*)  (ws + 16 * MB);
  u16*   W2T  = (u16*)  (ws + 18 * MB);
  u16*   WqT  = (u16*)  (ws + 20 * MB);
  u16*   WkT  = (u16*)  (ws + 22 * MB);
  u16*   WvT  = (u16*)  (ws + 24 * MB);
  u16*   Qb   = (u16*)  (ws + 26 * MB);
  u16*   Kb   = (u16*)  (ws + 42 * MB);
  u16*   VT   = (u16*)  (ws + 58 * MB);
  float* Sc   = (float*)(ws + 0 * MB);     // aliases xb (dead after QKV)
  u16*   Pb   = (u16*)  (ws + 74 * MB);
  float* attn = (float*)(ws + 82 * MB);
  float* hres = (float*)(ws + 114 * MB);
  u16*   hb   = Qb;                        // alias: Q dead after attention
  u16*   tb   = Kb;                        // alias: K dead after attention

  // prep: convert x, transpose+convert weights
  conv_x<<<(TOKS * DIMN) / 1024, 256, 0, stream>>>(x, xb);
  dim3 tblk(32, 8);
  transpose_w<<<dim3(32, 32), tblk, 0, stream>>>(Wq, WqT);
  transpose_w<<<dim3(32, 32), tblk, 0, stream>>>(Wk, WkT);
  transpose_w<<<dim3(32, 32), tblk, 0, stream>>>(Wv, WvT);
  transpose_w<<<dim3(32, 32), tblk, 0, stream>>>(W1, W1T);
  transpose_w<<<dim3(32, 32), tblk, 0, stream>>>(W2, W2T);

  // QKV projections
  gemm_bt<1><<<dim3(64, 8), 256, 0, stream>>>(xb, WqT, nullptr, Qb, bq,
                                              TOKS, DIMN, DIMN, DIMN);
  gemm_bt<1><<<dim3(64, 8), 256, 0, stream>>>(xb, WkT, nullptr, Kb, bk,
                                              TOKS, DIMN, DIMN, DIMN);
  gemm_bt<2><<<dim3(64, 8), 256, 0, stream>>>(xb, WvT, nullptr, VT, bv,
                                              TOKS, DIMN, DIMN, DIMN);

  // attention, per batch: scores = Q K^T ; P = softmax(scores/8) ; attn = P V
  for (int b = 0; b < NBAT; ++b) {
    const size_t tok_off = (size_t)b * SEQ * DIMN;
    gemm_bt<0><<<dim3(16, 16), 256, 0, stream>>>(Qb + tok_off, Kb + tok_off,
                                                 Sc, nullptr, nullptr,
                                                 SEQ, SEQ, DIMN, SEQ);
    softmax_rows<<<SEQ, 256, 0, stream>>>(Sc, Pb);
    gemm_bt<0><<<dim3(16, 8), 256, 0, stream>>>(Pb, VT + (size_t)b * DIMN * SEQ,
                                                attn + tok_off, nullptr, nullptr,
                                                SEQ, DIMN, SEQ, DIMN);
  }

  // at = LN(attn + x); h = LN(at + x)  -> hres (f32) + hb (bf16)
  ln1_fused<<<TOKS, 256, 0, stream>>>(attn, x, g_at, b_at, g_ln, b_ln, hres, hb);

  // FFN: t = gelu(h@W1 + c1) bf16 ; u = gelu(t@W2 + c2) f32 (reuses attn buf)
  gemm_bt<4><<<dim3(64, 8), 256, 0, stream>>>(hb, W1T, nullptr, tb, c1,
                                              TOKS, DIMN, DIMN, DIMN);
  gemm_bt<5><<<dim3(64, 8), 256, 0, stream>>>(tb, W2T, attn, nullptr, c2,
                                              TOKS, DIMN, DIMN, DIMN);

  // out = LN(u + h)
  ln2_final<<<TOKS, 256, 0, stream>>>(attn, hres, g_ln, b_ln, out);
}

// Round 3
// 422.462 us; speedup vs baseline: 1.3555x; 1.3555x over previous
//
#include <hip/hip_runtime.h>
#include <cstdint>
#include <cstddef>

// Problem constants
#define DIMN 1024
#define SEQ  2048
#define NBAT 4
#define TOKS (NBAT * SEQ)   // 8192

typedef unsigned short u16;
typedef unsigned int   u32;

typedef __bf16 bf16x8 __attribute__((ext_vector_type(8)));
typedef float  f32x4  __attribute__((ext_vector_type(4)));

#define AS1 __attribute__((address_space(1)))
#define AS3 __attribute__((address_space(3)))

// ---- helpers ----------------------------------------------------------------

__device__ __forceinline__ u16 f2b(float f) {
  union { float f; u32 u; } v; v.f = f;
  u32 r = v.u + 0x7fffu + ((v.u >> 16) & 1u);   // round-to-nearest-even
  return (u16)(r >> 16);
}

__device__ __forceinline__ float gelu_exact(float v) {
  return 0.5f * v * (1.0f + erff(v * 0.70710678118654752f));
}

__device__ __forceinline__ void blk_sum2(float& a, float& b, float* sm) {
  #pragma unroll
  for (int o = 32; o >= 1; o >>= 1) {
    a += __shfl_xor(a, o, 64);
    b += __shfl_xor(b, o, 64);
  }
  int w = threadIdx.x >> 6;
  if ((threadIdx.x & 63) == 0) { sm[w] = a; sm[4 + w] = b; }
  __syncthreads();
  a = sm[0] + sm[1] + sm[2] + sm[3];
  b = sm[4] + sm[5] + sm[6] + sm[7];
  __syncthreads();
}

__device__ __forceinline__ float blk_max(float a, float* sm) {
  #pragma unroll
  for (int o = 32; o >= 1; o >>= 1) a = fmaxf(a, __shfl_xor(a, o, 64));
  int w = threadIdx.x >> 6;
  if ((threadIdx.x & 63) == 0) sm[w] = a;
  __syncthreads();
  float r = fmaxf(fmaxf(sm[0], sm[1]), fmaxf(sm[2], sm[3]));
  __syncthreads();
  return r;
}

__device__ __forceinline__ float blk_sum1(float a, float* sm) {
  #pragma unroll
  for (int o = 32; o >= 1; o >>= 1) a += __shfl_xor(a, o, 64);
  int w = threadIdx.x >> 6;
  if ((threadIdx.x & 63) == 0) sm[w] = a;
  __syncthreads();
  float r = sm[0] + sm[1] + sm[2] + sm[3];
  __syncthreads();
  return r;
}

// ---- prep kernels -----------------------------------------------------------

__global__ __launch_bounds__(256) void conv_x(const float* __restrict__ x,
                                              u16* __restrict__ xb) {
  size_t i = ((size_t)blockIdx.x * 256 + threadIdx.x) * 4;
  float4 v = *(const float4*)(x + i);
  uint2 o;
  o.x = (u32)f2b(v.x) | ((u32)f2b(v.y) << 16);
  o.y = (u32)f2b(v.z) | ((u32)f2b(v.w) << 16);
  *(uint2*)(xb + i) = o;
}

// All 5 weight transposes in one dispatch: W [K][N] f32 -> WT [N][K] bf16
__global__ __launch_bounds__(256) void transpose_w5(
    const float* __restrict__ Wq, const float* __restrict__ Wk,
    const float* __restrict__ Wv, const float* __restrict__ W1,
    const float* __restrict__ W2,
    u16* __restrict__ WqT, u16* __restrict__ WkT, u16* __restrict__ WvT,
    u16* __restrict__ W1T, u16* __restrict__ W2T)
{
  const float* W; u16* T;
  switch (blockIdx.z) {
    case 0: W = Wq; T = WqT; break;
    case 1: W = Wk; T = WkT; break;
    case 2: W = Wv; T = WvT; break;
    case 3: W = W1; T = W1T; break;
    default: W = W2; T = W2T; break;
  }
  __shared__ float t[32][33];
  int tx = threadIdx.x, ty = threadIdx.y;
  int k0 = blockIdx.x * 32, n0 = blockIdx.y * 32;
  #pragma unroll
  for (int j = 0; j < 32; j += 8)
    t[ty + j][tx] = W[(size_t)(k0 + ty + j) * DIMN + n0 + tx];
  __syncthreads();
  #pragma unroll
  for (int j = 0; j < 32; j += 8)
    T[(size_t)(n0 + ty + j) * DIMN + k0 + tx] = f2b(t[tx][ty + j]);
}

// ---- MFMA GEMM: C[M,N] = A[M,K] * B^T  (B given as [N][K]) ------------------
// 128x128 tile, BK=64, 256 threads = 4 waves, wave tile 64x64 (4x4 of 16x16x32).
// Staging via global_load_lds width=16 (m97 recipe). LDS rows are unpadded
// (64 elems = 128 B); bank conflicts broken by XOR chunk swizzle:
//   LDS slot s of row r holds global 16B-chunk (s ^ (r&7)).
// grid.z batches with element strides sA/sB/sC.
// EPI: 0=f32 store; 1=+bias bf16; 2=+bias bf16 transposed (VT[b][d][tok]);
//      4=+bias GELU bf16; 5=+bias GELU f32
template <int EPI>
__global__ __launch_bounds__(256) void gemm_bt(
    const u16* __restrict__ A, const u16* __restrict__ Bm,
    float* __restrict__ Cf, u16* __restrict__ Cb,
    const float* __restrict__ bias,
    int M, int N, int K, int ldc,
    size_t sA, size_t sB, size_t sC)
{
  __shared__ u16 As[128 * 64];   // 16 KiB
  __shared__ u16 Bs[128 * 64];

  const int tid  = threadIdx.x;
  const int bm0  = blockIdx.x * 128;
  const int bn0  = blockIdx.y * 128;
  A  += (size_t)blockIdx.z * sA;
  Bm += (size_t)blockIdx.z * sB;
  const int wave = tid >> 6, lane = tid & 63;
  const int wm   = (wave >> 1) * 64, wn = (wave & 1) * 64;
  const int l16  = lane & 15, quad = lane >> 4;

  f32x4 acc[4][4] = {};

  for (int k0 = 0; k0 < K; k0 += 64) {
    // async stage: 1024 chunks of 16B per tile; wave w, call j covers chunks
    // [ (w*4+j)*64 , +64 ); lane's chunk c -> row r=c>>3, swizzled slot c&7
    // holds global chunk (c&7)^(r&7).
    #pragma unroll
    for (int j = 0; j < 4; ++j) {
      const int c  = wave * 256 + j * 64 + lane;
      const int r  = c >> 3;
      const int cg = (c & 7) ^ (r & 7);
      const u16* gA = A  + (size_t)(bm0 + r) * K + k0 + cg * 8;
      const u16* gB = Bm + (size_t)(bn0 + r) * K + k0 + cg * 8;
      u16* lA = As + (wave * 4 + j) * 512;   // wave-uniform base, +lane*16B in HW
      u16* lB = Bs + (wave * 4 + j) * 512;
      __builtin_amdgcn_global_load_lds((const AS1 void*)gA, (AS3 void*)lA, 16, 0, 0);
      __builtin_amdgcn_global_load_lds((const AS1 void*)gB, (AS3 void*)lB, 16, 0, 0);
    }
    __syncthreads();

    #pragma unroll
    for (int kk = 0; kk < 64; kk += 32) {
      const int kc = kk >> 3;
      const int sw = l16 & 7;
      bf16x8 af[4], bfr[4];
      #pragma unroll
      for (int t = 0; t < 4; ++t) {
        const int row = wm + t * 16 + l16;
        af[t] = *(const bf16x8*)(&As[row * 64 + (((kc + quad) ^ sw) << 3)]);
      }
      #pragma unroll
      for (int t = 0; t < 4; ++t) {
        const int row = wn + t * 16 + l16;
        bfr[t] = *(const bf16x8*)(&Bs[row * 64 + (((kc + quad) ^ sw) << 3)]);
      }
      #pragma unroll
      for (int mt = 0; mt < 4; ++mt)
        #pragma unroll
        for (int nt = 0; nt < 4; ++nt)
          acc[mt][nt] = __builtin_amdgcn_mfma_f32_16x16x32_bf16(
              af[mt], bfr[nt], acc[mt][nt], 0, 0, 0);
    }
    __syncthreads();
  }

  float* Cfz = Cf + (size_t)blockIdx.z * sC;
  u16*   Cbz = Cb + (size_t)blockIdx.z * sC;

  // epilogue: C/D layout col = lane&15, row = quad*4 + reg
  #pragma unroll
  for (int mt = 0; mt < 4; ++mt) {
    int grow0 = bm0 + wm + mt * 16 + quad * 4;
    #pragma unroll
    for (int nt = 0; nt < 4; ++nt) {
      int gcol = bn0 + wn + nt * 16 + l16;
      float bv = (EPI != 0) ? bias[gcol] : 0.0f;
      #pragma unroll
      for (int r = 0; r < 4; ++r) {
        float v  = acc[mt][nt][r] + bv;
        int grow = grow0 + r;
        if (EPI == 0) {
          Cfz[(size_t)grow * ldc + gcol] = v;
        } else if (EPI == 1) {
          Cbz[(size_t)grow * ldc + gcol] = f2b(v);
        } else if (EPI == 2) {
          // VT[b][d][tok]: b = grow>>11, tok = grow&2047, d = gcol
          Cbz[(size_t)((grow >> 11) * DIMN + gcol) * SEQ + (grow & 2047)] = f2b(v);
        } else if (EPI == 4) {
          Cbz[(size_t)grow * ldc + gcol] = f2b(gelu_exact(v));
        } else {  // 5
          Cfz[(size_t)grow * ldc + gcol] = gelu_exact(v);
        }
      }
    }
  }
}

// ---- softmax over rows of 2048, scale 1/8 folded in, write bf16 P -----------
__global__ __launch_bounds__(256) void softmax_rows(const float* __restrict__ Sc,
                                                    u16* __restrict__ P) {
  __shared__ float sm[8];
  int row = blockIdx.x, t = threadIdx.x;
  const float* s = Sc + (size_t)row * SEQ;
  float v[8];
  float mx = -1e30f;
  #pragma unroll
  for (int i = 0; i < 8; ++i) {
    v[i] = s[t + i * 256] * 0.125f;
    mx = fmaxf(mx, v[i]);
  }
  mx = blk_max(mx, sm);
  float sum = 0.0f;
  #pragma unroll
  for (int i = 0; i < 8; ++i) { v[i] = __expf(v[i] - mx); sum += v[i]; }
  sum = blk_sum1(sum, sm);
  float inv = 1.0f / sum;
  u16* p = P + (size_t)row * SEQ;
  #pragma unroll
  for (int i = 0; i < 8; ++i) p[t + i * 256] = f2b(v[i] * inv);
}

// ---- LN(attn + x)*g_at+b_at -> at; LN(at + x)*g_ln+b_ln -> h (f32 + bf16) ---
__global__ __launch_bounds__(256) void ln1_fused(
    const float* __restrict__ attn, const float* __restrict__ x,
    const float* __restrict__ g_at, const float* __restrict__ b_at,
    const float* __restrict__ g_ln, const float* __restrict__ b_ln,
    float* __restrict__ hres, u16* __restrict__ hb)
{
  __shared__ float sm[8];
  int row = blockIdx.x, t = threadIdx.x;
  size_t base = (size_t)row * DIMN;
  float y[4], xr[4];
  float s = 0.0f, s2 = 0.0f;
  #pragma unroll
  for (int i = 0; i < 4; ++i) {
    int c = t + i * 256;
    xr[i] = x[base + c];
    y[i]  = attn[base + c] + xr[i];
    s += y[i]; s2 += y[i] * y[i];
  }
  blk_sum2(s, s2, sm);
  float m  = s * (1.0f / DIMN);
  float rs = rsqrtf(s2 * (1.0f / DIMN) - m * m + 1e-5f);
  float z[4];
  s = 0.0f; s2 = 0.0f;
  #pragma unroll
  for (int i = 0; i < 4; ++i) {
    int c = t + i * 256;
    float at = (y[i] - m) * rs * g_at[c] + b_at[c];
    z[i] = at + xr[i];
    s += z[i]; s2 += z[i] * z[i];
  }
  blk_sum2(s, s2, sm);
  float m2  = s * (1.0f / DIMN);
  float rs2 = rsqrtf(s2 * (1.0f / DIMN) - m2 * m2 + 1e-5f);
  #pragma unroll
  for (int i = 0; i < 4; ++i) {
    int c = t + i * 256;
    float h = (z[i] - m2) * rs2 * g_ln[c] + b_ln[c];
    hres[base + c] = h;
    hb[base + c]   = f2b(h);
  }
}

// ---- out = LN(u + hres)*g_ln + b_ln ----------------------------------------
__global__ __launch_bounds__(256) void ln2_final(
    const float* __restrict__ u, const float* __restrict__ hres,
    const float* __restrict__ g, const float* __restrict__ bb,
    float* __restrict__ out)
{
  __shared__ float sm[8];
  int row = blockIdx.x, t = threadIdx.x;
  size_t base = (size_t)row * DIMN;
  float y[4];
  float s = 0.0f, s2 = 0.0f;
  #pragma unroll
  for (int i = 0; i < 4; ++i) {
    int c = t + i * 256;
    y[i] = u[base + c] + hres[base + c];
    s += y[i]; s2 += y[i] * y[i];
  }
  blk_sum2(s, s2, sm);
  float m  = s * (1.0f / DIMN);
  float rs = rsqrtf(s2 * (1.0f / DIMN) - m * m + 1e-5f);
  #pragma unroll
  for (int i = 0; i < 4; ++i) {
    int c = t + i * 256;
    out[base + c] = (y[i] - m) * rs * g[c] + bb[c];
  }
}

// ---- launch -----------------------------------------------------------------

extern "C" void kernel_launch(void* const* d_in, const int* in_sizes, int n_in,
                              void* d_out, int out_size, void* d_ws, size_t ws_size,
                              hipStream_t stream)
{
  const float* x    = (const float*)d_in[0];
  const float* Wq   = (const float*)d_in[1];
  const float* bq   = (const float*)d_in[2];
  const float* Wk   = (const float*)d_in[3];
  const float* bk   = (const float*)d_in[4];
  const float* Wv   = (const float*)d_in[5];
  const float* bv   = (const float*)d_in[6];
  const float* g_at = (const float*)d_in[7];
  const float* b_at = (const float*)d_in[8];
  const float* g_ln = (const float*)d_in[9];
  const float* b_ln = (const float*)d_in[10];
  const float* W1   = (const float*)d_in[11];
  const float* c1   = (const float*)d_in[12];
  const float* W2   = (const float*)d_in[13];
  const float* c2   = (const float*)d_in[14];
  float* out = (float*)d_out;

  char* ws = (char*)d_ws;
  const size_t MB = 1u << 20;
  const bool big = ws_size >= 172 * MB;   // round-2 counters: ws ~256 MiB

  // common region (both paths)
  u16* xb  = (u16*)(ws + 0 * MB);     // dead after QKV
  u16* W1T = (u16*)(ws + 16 * MB);
  u16* W2T = (u16*)(ws + 18 * MB);
  u16* WqT = (u16*)(ws + 20 * MB);
  u16* WkT = (u16*)(ws + 22 * MB);
  u16* WvT = (u16*)(ws + 24 * MB);
  u16* Qb  = (u16*)(ws + 26 * MB);    // dead after scores -> hb
  u16* Kb  = (u16*)(ws + 42 * MB);    // dead after scores -> tb
  u16* VT  = (u16*)(ws + 58 * MB);    // [b][d][tok]
  u16* hb  = Qb;
  u16* tb  = Kb;

  // prep
  conv_x<<<(TOKS * DIMN) / 1024, 256, 0, stream>>>(x, xb);
  transpose_w5<<<dim3(32, 32, 5), dim3(32, 8), 0, stream>>>(
      Wq, Wk, Wv, W1, W2, WqT, WkT, WvT, W1T, W2T);

  // QKV projections
  gemm_bt<1><<<dim3(64, 8), 256, 0, stream>>>(xb, WqT, nullptr, Qb, bq,
                                              TOKS, DIMN, DIMN, DIMN, 0, 0, 0);
  gemm_bt<1><<<dim3(64, 8), 256, 0, stream>>>(xb, WkT, nullptr, Kb, bk,
                                              TOKS, DIMN, DIMN, DIMN, 0, 0, 0);
  gemm_bt<2><<<dim3(64, 8), 256, 0, stream>>>(xb, WvT, nullptr, VT, bv,
                                              TOKS, DIMN, DIMN, DIMN, 0, 0, 0);

  float* attn;
  float* hres;

  if (big) {
    // big path: batched attention via grid.z
    //  74..138 Sc (f32, all 4 batches)  -> dead after softmax
    // 138..170 Pb (bf16, all 4 batches)
    //  attn aliases Sc[0..32MB), hres aliases Sc[32..64MB)
    float* Sc = (float*)(ws + 74 * MB);
    u16*   Pb = (u16*) (ws + 138 * MB);
    attn = (float*)(ws + 74 * MB);
    hres = (float*)(ws + 106 * MB);

    gemm_bt<0><<<dim3(16, 16, NBAT), 256, 0, stream>>>(
        Qb, Kb, Sc, nullptr, nullptr, SEQ, SEQ, DIMN, SEQ,
        (size_t)SEQ * DIMN, (size_t)SEQ * DIMN, (size_t)SEQ * SEQ);
    softmax_rows<<<TOKS, 256, 0, stream>>>(Sc, Pb);
    gemm_bt<0><<<dim3(16, 8, NBAT), 256, 0, stream>>>(
        Pb, VT, attn, nullptr, nullptr, SEQ, DIMN, SEQ, DIMN,
        (size_t)SEQ * SEQ, (size_t)DIMN * SEQ, (size_t)SEQ * DIMN);
  } else {
    // fallback (round-2 layout, per-batch loop): peak 146 MiB
    float* Sc = (float*)(ws + 0 * MB);    // aliases xb
    u16*   Pb = (u16*) (ws + 74 * MB);
    attn = (float*)(ws + 82 * MB);
    hres = (float*)(ws + 114 * MB);
    for (int b = 0; b < NBAT; ++b) {
      const size_t tok_off = (size_t)b * SEQ * DIMN;
      gemm_bt<0><<<dim3(16, 16), 256, 0, stream>>>(
          Qb + tok_off, Kb + tok_off, Sc, nullptr, nullptr,
          SEQ, SEQ, DIMN, SEQ, 0, 0, 0);
      softmax_rows<<<SEQ, 256, 0, stream>>>(Sc, Pb);
      gemm_bt<0><<<dim3(16, 8), 256, 0, stream>>>(
          Pb, VT + (size_t)b * DIMN * SEQ, attn + tok_off, nullptr, nullptr,
          SEQ, DIMN, SEQ, DIMN, 0, 0, 0);
    }
  }

  // at = LN(attn + x); h = LN(at + x)  -> hres (f32) + hb (bf16)
  ln1_fused<<<TOKS, 256, 0, stream>>>(attn, x, g_at, b_at, g_ln, b_ln, hres, hb);

  // FFN: t = gelu(h@W1 + c1) bf16 ; u = gelu(t@W2 + c2) f32 (reuses attn buf)
  gemm_bt<4><<<dim3(64, 8), 256, 0, stream>>>(hb, W1T, nullptr, tb, c1,
                                              TOKS, DIMN, DIMN, DIMN, 0, 0, 0);
  gemm_bt<5><<<dim3(64, 8), 256, 0, stream>>>(tb, W2T, attn, nullptr, c2,
                                              TOKS, DIMN, DIMN, DIMN, 0, 0, 0);

  // out = LN(u + h)
  ln2_final<<<TOKS, 256, 0, stream>>>(attn, hres, g_ln, b_ln, out);
}

// Round 4
// 407.592 us; speedup vs baseline: 1.4050x; 1.0365x over previous
//
#include <hip/hip_runtime.h>
#include <cstdint>
#include <cstddef>

// Problem constants
#define DIMN 1024
#define SEQ  2048
#define NBAT 4
#define TOKS (NBAT * SEQ)   // 8192

typedef unsigned short u16;
typedef unsigned int   u32;

typedef __bf16 bf16x8 __attribute__((ext_vector_type(8)));
typedef float  f32x4  __attribute__((ext_vector_type(4)));

#define AS1 __attribute__((address_space(1)))
#define AS3 __attribute__((address_space(3)))

// ---- helpers ----------------------------------------------------------------

__device__ __forceinline__ u16 f2b(float f) {
  union { float f; u32 u; } v; v.f = f;
  u32 r = v.u + 0x7fffu + ((v.u >> 16) & 1u);   // round-to-nearest-even
  return (u16)(r >> 16);
}

__device__ __forceinline__ float b2f(u16 b) {
  union { u32 u; float f; } v; v.u = ((u32)b) << 16;
  return v.f;
}

__device__ __forceinline__ float gelu_exact(float v) {
  return 0.5f * v * (1.0f + erff(v * 0.70710678118654752f));
}

__device__ __forceinline__ void blk_sum2(float& a, float& b, float* sm) {
  #pragma unroll
  for (int o = 32; o >= 1; o >>= 1) {
    a += __shfl_xor(a, o, 64);
    b += __shfl_xor(b, o, 64);
  }
  int w = threadIdx.x >> 6;
  if ((threadIdx.x & 63) == 0) { sm[w] = a; sm[4 + w] = b; }
  __syncthreads();
  a = sm[0] + sm[1] + sm[2] + sm[3];
  b = sm[4] + sm[5] + sm[6] + sm[7];
  __syncthreads();
}

__device__ __forceinline__ float blk_max(float a, float* sm) {
  #pragma unroll
  for (int o = 32; o >= 1; o >>= 1) a = fmaxf(a, __shfl_xor(a, o, 64));
  int w = threadIdx.x >> 6;
  if ((threadIdx.x & 63) == 0) sm[w] = a;
  __syncthreads();
  float r = fmaxf(fmaxf(sm[0], sm[1]), fmaxf(sm[2], sm[3]));
  __syncthreads();
  return r;
}

__device__ __forceinline__ float blk_sum1(float a, float* sm) {
  #pragma unroll
  for (int o = 32; o >= 1; o >>= 1) a += __shfl_xor(a, o, 64);
  int w = threadIdx.x >> 6;
  if ((threadIdx.x & 63) == 0) sm[w] = a;
  __syncthreads();
  float r = sm[0] + sm[1] + sm[2] + sm[3];
  __syncthreads();
  return r;
}

// ---- prep kernels -----------------------------------------------------------

__global__ __launch_bounds__(256) void conv_x(const float* __restrict__ x,
                                              u16* __restrict__ xb) {
  size_t i = ((size_t)blockIdx.x * 256 + threadIdx.x) * 4;
  float4 v = *(const float4*)(x + i);
  uint2 o;
  o.x = (u32)f2b(v.x) | ((u32)f2b(v.y) << 16);
  o.y = (u32)f2b(v.z) | ((u32)f2b(v.w) << 16);
  *(uint2*)(xb + i) = o;
}

// All 5 weight transposes in one dispatch: W [K][N] f32 -> WT [N][K] bf16.
// Wq/Wk/Wv write into one contiguous [3072][1024] block (QKV merged B).
__global__ __launch_bounds__(256) void transpose_w5(
    const float* __restrict__ Wq, const float* __restrict__ Wk,
    const float* __restrict__ Wv, const float* __restrict__ W1,
    const float* __restrict__ W2,
    u16* __restrict__ Wqkv, u16* __restrict__ W1T, u16* __restrict__ W2T)
{
  const float* W; u16* T;
  switch (blockIdx.z) {
    case 0: W = Wq; T = Wqkv;                      break;
    case 1: W = Wk; T = Wqkv + 1 * DIMN * DIMN;    break;
    case 2: W = Wv; T = Wqkv + 2 * DIMN * DIMN;    break;
    case 3: W = W1; T = W1T;                       break;
    default: W = W2; T = W2T;                      break;
  }
  __shared__ float t[32][33];
  int tx = threadIdx.x, ty = threadIdx.y;
  int k0 = blockIdx.x * 32, n0 = blockIdx.y * 32;
  #pragma unroll
  for (int j = 0; j < 32; j += 8)
    t[ty + j][tx] = W[(size_t)(k0 + ty + j) * DIMN + n0 + tx];
  __syncthreads();
  #pragma unroll
  for (int j = 0; j < 32; j += 8)
    T[(size_t)(n0 + ty + j) * DIMN + k0 + tx] = f2b(t[tx][ty + j]);
}

// Vb[b][tok][d] bf16 -> VT[b][d][tok] bf16 (per-batch 2048x1024 transpose)
__global__ __launch_bounds__(256) void transpose_v(const u16* __restrict__ Vb,
                                                   u16* __restrict__ VT) {
  __shared__ u16 t[32][33];
  int tx = threadIdx.x, ty = threadIdx.y;
  int d0 = blockIdx.x * 32, t0 = blockIdx.y * 32;
  const u16* src = Vb + (size_t)blockIdx.z * SEQ * DIMN;
  u16*       dst = VT + (size_t)blockIdx.z * DIMN * SEQ;
  #pragma unroll
  for (int j = 0; j < 32; j += 8)
    t[ty + j][tx] = src[(size_t)(t0 + ty + j) * DIMN + d0 + tx];
  __syncthreads();
  #pragma unroll
  for (int j = 0; j < 32; j += 8)
    dst[(size_t)(d0 + ty + j) * SEQ + t0 + tx] = t[tx][ty + j];
}

// ---- MFMA GEMM: C[M,N] = A[M,K] * B^T  (B given as [N][K]) ------------------
// 128x128 tile, BK=64, 256 threads = 4 waves, wave tile 64x64 (4x4 of 16x16x32).
// Staging via global_load_lds width=16 (m97 recipe); XOR chunk swizzle for
// conflict-free ds_read_b128 (round-3: SQ_LDS_BANK_CONFLICT == 0).
// XCD-aware block swizzle: flat id -> (xcd, i) -> m-major runs per XCD so
// B-tiles stay resident in the per-XCD L2.
// grid.z batches with element strides sA/sB/sC.
// EPI: 3 = QKV routed (+bias per 1024-segment, bf16 to Cb/Cb2/Cb3)
//      4 = +bias, GELU, bf16
//      6 = plain bf16
template <int EPI>
__global__ __launch_bounds__(256) void gemm_bt(
    const u16* __restrict__ A, const u16* __restrict__ Bm,
    u16* __restrict__ Cb, u16* __restrict__ Cb2, u16* __restrict__ Cb3,
    const float* __restrict__ bias, const float* __restrict__ bias2,
    const float* __restrict__ bias3,
    int M, int N, int K, int ldc,
    size_t sA, size_t sB, size_t sC)
{
  __shared__ u16 As[128 * 64];   // 16 KiB
  __shared__ u16 Bs[128 * 64];

  const int tid = threadIdx.x;

  // XCD swizzle (all grids have gridDim.x*gridDim.y % 8 == 0)
  const int Tt   = gridDim.x * gridDim.y;
  const int id   = blockIdx.y * gridDim.x + blockIdx.x;
  const int per  = Tt >> 3;
  const int flat = (id & 7) * per + (id >> 3);
  const int bm0  = (flat % gridDim.x) * 128;
  const int bn0  = (flat / gridDim.x) * 128;

  A  += (size_t)blockIdx.z * sA;
  Bm += (size_t)blockIdx.z * sB;
  const int wave = tid >> 6, lane = tid & 63;
  const int wm   = (wave >> 1) * 64, wn = (wave & 1) * 64;
  const int l16  = lane & 15, quad = lane >> 4;

  f32x4 acc[4][4] = {};

  for (int k0 = 0; k0 < K; k0 += 64) {
    #pragma unroll
    for (int j = 0; j < 4; ++j) {
      const int c  = wave * 256 + j * 64 + lane;
      const int r  = c >> 3;
      const int cg = (c & 7) ^ (r & 7);
      const u16* gA = A  + (size_t)(bm0 + r) * K + k0 + cg * 8;
      const u16* gB = Bm + (size_t)(bn0 + r) * K + k0 + cg * 8;
      u16* lA = As + (wave * 4 + j) * 512;   // wave-uniform base, +lane*16B in HW
      u16* lB = Bs + (wave * 4 + j) * 512;
      __builtin_amdgcn_global_load_lds((const AS1 void*)gA, (AS3 void*)lA, 16, 0, 0);
      __builtin_amdgcn_global_load_lds((const AS1 void*)gB, (AS3 void*)lB, 16, 0, 0);
    }
    __syncthreads();

    #pragma unroll
    for (int kk = 0; kk < 64; kk += 32) {
      const int kc = kk >> 3;
      const int sw = l16 & 7;
      bf16x8 af[4], bfr[4];
      #pragma unroll
      for (int t = 0; t < 4; ++t) {
        const int row = wm + t * 16 + l16;
        af[t] = *(const bf16x8*)(&As[row * 64 + (((kc + quad) ^ sw) << 3)]);
      }
      #pragma unroll
      for (int t = 0; t < 4; ++t) {
        const int row = wn + t * 16 + l16;
        bfr[t] = *(const bf16x8*)(&Bs[row * 64 + (((kc + quad) ^ sw) << 3)]);
      }
      #pragma unroll
      for (int mt = 0; mt < 4; ++mt)
        #pragma unroll
        for (int nt = 0; nt < 4; ++nt)
          acc[mt][nt] = __builtin_amdgcn_mfma_f32_16x16x32_bf16(
              af[mt], bfr[nt], acc[mt][nt], 0, 0, 0);
    }
    __syncthreads();
  }

  u16* Cbz = Cb + (size_t)blockIdx.z * sC;

  // epilogue: C/D layout col = lane&15, row = quad*4 + reg
  #pragma unroll
  for (int mt = 0; mt < 4; ++mt) {
    int grow0 = bm0 + wm + mt * 16 + quad * 4;
    #pragma unroll
    for (int nt = 0; nt < 4; ++nt) {
      int gcol = bn0 + wn + nt * 16 + l16;
      if (EPI == 3) {
        const int seg = gcol >> 10;
        const int col = gcol & 1023;
        const float* bp = (seg == 0) ? bias : (seg == 1) ? bias2 : bias3;
        u16*         cp = (seg == 0) ? Cb   : (seg == 1) ? Cb2   : Cb3;
        float bv = bp[col];
        #pragma unroll
        for (int r = 0; r < 4; ++r)
          cp[(size_t)(grow0 + r) * ldc + col] = f2b(acc[mt][nt][r] + bv);
      } else if (EPI == 4) {
        float bv = bias[gcol];
        #pragma unroll
        for (int r = 0; r < 4; ++r)
          Cbz[(size_t)(grow0 + r) * ldc + gcol] =
              f2b(gelu_exact(acc[mt][nt][r] + bv));
      } else {  // 6
        #pragma unroll
        for (int r = 0; r < 4; ++r)
          Cbz[(size_t)(grow0 + r) * ldc + gcol] = f2b(acc[mt][nt][r]);
      }
    }
  }
}

// ---- softmax over rows of 2048 (bf16 in), scale 1/8, write bf16 P -----------
__global__ __launch_bounds__(256) void softmax_rows(const u16* __restrict__ Sc,
                                                    u16* __restrict__ P) {
  __shared__ float sm[8];
  int row = blockIdx.x, t = threadIdx.x;
  const u16* s = Sc + (size_t)row * SEQ;
  uint4 raw = *(const uint4*)(s + t * 8);
  float v[8];
  #pragma unroll
  for (int m = 0; m < 4; ++m) {
    u32 w = ((const u32*)&raw)[m];
    v[2 * m]     = b2f((u16)(w & 0xffff)) * 0.125f;
    v[2 * m + 1] = b2f((u16)(w >> 16)) * 0.125f;
  }
  float mx = -1e30f;
  #pragma unroll
  for (int i = 0; i < 8; ++i) mx = fmaxf(mx, v[i]);
  mx = blk_max(mx, sm);
  float sum = 0.0f;
  #pragma unroll
  for (int i = 0; i < 8; ++i) { v[i] = __expf(v[i] - mx); sum += v[i]; }
  sum = blk_sum1(sum, sm);
  float inv = 1.0f / sum;
  uint4 o;
  #pragma unroll
  for (int m = 0; m < 4; ++m)
    ((u32*)&o)[m] = (u32)f2b(v[2 * m] * inv) | ((u32)f2b(v[2 * m + 1] * inv) << 16);
  *(uint4*)(P + (size_t)row * SEQ + t * 8) = o;
}

// ---- h = LN( LN(attn+x)*g_at+b_at + x )*g_ln+b_ln  -> hres bf16 -------------
__global__ __launch_bounds__(256) void ln1_fused(
    const u16* __restrict__ attn, const u16* __restrict__ xb,
    const float* __restrict__ g_at, const float* __restrict__ b_at,
    const float* __restrict__ g_ln, const float* __restrict__ b_ln,
    u16* __restrict__ hres)
{
  __shared__ float sm[8];
  int row = blockIdx.x, t = threadIdx.x;
  size_t base = (size_t)row * DIMN;
  uint2 ar = *(const uint2*)(attn + base + t * 4);
  uint2 xr4 = *(const uint2*)(xb + base + t * 4);
  float y[4], xr[4];
  float s = 0.0f, s2 = 0.0f;
  #pragma unroll
  for (int i = 0; i < 4; ++i) {
    u32 aw = ((const u32*)&ar)[i >> 1];
    u32 xw = ((const u32*)&xr4)[i >> 1];
    float av = b2f((u16)((i & 1) ? (aw >> 16) : (aw & 0xffff)));
    xr[i]    = b2f((u16)((i & 1) ? (xw >> 16) : (xw & 0xffff)));
    y[i] = av + xr[i];
    s += y[i]; s2 += y[i] * y[i];
  }
  blk_sum2(s, s2, sm);
  float m  = s * (1.0f / DIMN);
  float rs = rsqrtf(s2 * (1.0f / DIMN) - m * m + 1e-5f);
  float z[4];
  s = 0.0f; s2 = 0.0f;
  #pragma unroll
  for (int i = 0; i < 4; ++i) {
    int c = t * 4 + i;
    float at = (y[i] - m) * rs * g_at[c] + b_at[c];
    z[i] = at + xr[i];
    s += z[i]; s2 += z[i] * z[i];
  }
  blk_sum2(s, s2, sm);
  float m2  = s * (1.0f / DIMN);
  float rs2 = rsqrtf(s2 * (1.0f / DIMN) - m2 * m2 + 1e-5f);
  uint2 o;
  #pragma unroll
  for (int i = 0; i < 2; ++i) {
    int c = t * 4 + 2 * i;
    float h0 = (z[2 * i]     - m2) * rs2 * g_ln[c]     + b_ln[c];
    float h1 = (z[2 * i + 1] - m2) * rs2 * g_ln[c + 1] + b_ln[c + 1];
    ((u32*)&o)[i] = (u32)f2b(h0) | ((u32)f2b(h1) << 16);
  }
  *(uint2*)(hres + base + t * 4) = o;
}

// ---- out = LN(u + hres)*g_ln + b_ln  (bf16 in, f32 out) ---------------------
__global__ __launch_bounds__(256) void ln2_final(
    const u16* __restrict__ u, const u16* __restrict__ hres,
    const float* __restrict__ g, const float* __restrict__ bb,
    float* __restrict__ out)
{
  __shared__ float sm[8];
  int row = blockIdx.x, t = threadIdx.x;
  size_t base = (size_t)row * DIMN;
  uint2 ur = *(const uint2*)(u + base + t * 4);
  uint2 hr = *(const uint2*)(hres + base + t * 4);
  float y[4];
  float s = 0.0f, s2 = 0.0f;
  #pragma unroll
  for (int i = 0; i < 4; ++i) {
    u32 uw = ((const u32*)&ur)[i >> 1];
    u32 hw = ((const u32*)&hr)[i >> 1];
    float uv = b2f((u16)((i & 1) ? (uw >> 16) : (uw & 0xffff)));
    float hv = b2f((u16)((i & 1) ? (hw >> 16) : (hw & 0xffff)));
    y[i] = uv + hv;
    s += y[i]; s2 += y[i] * y[i];
  }
  blk_sum2(s, s2, sm);
  float m  = s * (1.0f / DIMN);
  float rs = rsqrtf(s2 * (1.0f / DIMN) - m * m + 1e-5f);
  float4 o;
  o.x = (y[0] - m) * rs * g[t * 4 + 0] + bb[t * 4 + 0];
  o.y = (y[1] - m) * rs * g[t * 4 + 1] + bb[t * 4 + 1];
  o.z = (y[2] - m) * rs * g[t * 4 + 2] + bb[t * 4 + 2];
  o.w = (y[3] - m) * rs * g[t * 4 + 3] + bb[t * 4 + 3];
  *(float4*)(out + base + t * 4) = o;
}

// ---- launch -----------------------------------------------------------------

extern "C" void kernel_launch(void* const* d_in, const int* in_sizes, int n_in,
                              void* d_out, int out_size, void* d_ws, size_t ws_size,
                              hipStream_t stream)
{
  const float* x    = (const float*)d_in[0];
  const float* Wq   = (const float*)d_in[1];
  const float* bq   = (const float*)d_in[2];
  const float* Wk   = (const float*)d_in[3];
  const float* bk   = (const float*)d_in[4];
  const float* Wv   = (const float*)d_in[5];
  const float* bv   = (const float*)d_in[6];
  const float* g_at = (const float*)d_in[7];
  const float* b_at = (const float*)d_in[8];
  const float* g_ln = (const float*)d_in[9];
  const float* b_ln = (const float*)d_in[10];
  const float* W1   = (const float*)d_in[11];
  const float* c1   = (const float*)d_in[12];
  const float* W2   = (const float*)d_in[13];
  const float* c2   = (const float*)d_in[14];
  float* out = (float*)d_out;

  // workspace layout (1 MiB units), peak 154 MiB (round-3 confirmed >=172 MiB):
  //   0..16  xb      (alive through ln1)
  //  16..18  W1T   18..20 W2T   20..26 WqkvT [3072][1024]
  //  26..42  Qb      (dead after scores)
  //  42..58  Kb      (dead after scores; tb alias for FFN mid)
  //  58..74  Vb      (dead after transpose_v; ub alias for FFN out)
  //  74..90  VT
  //  90..122 Sc bf16 (dead after softmax; attn 90..106, hres 106..122 alias)
  // 122..154 Pb bf16
  char* ws = (char*)d_ws;
  const size_t MB = 1u << 20;
  u16* xb    = (u16*)(ws + 0 * MB);
  u16* W1T   = (u16*)(ws + 16 * MB);
  u16* W2T   = (u16*)(ws + 18 * MB);
  u16* WqkvT = (u16*)(ws + 20 * MB);
  u16* Qb    = (u16*)(ws + 26 * MB);
  u16* Kb    = (u16*)(ws + 42 * MB);
  u16* Vb    = (u16*)(ws + 58 * MB);
  u16* VT    = (u16*)(ws + 74 * MB);
  u16* Sc    = (u16*)(ws + 90 * MB);
  u16* attn  = (u16*)(ws + 90 * MB);
  u16* hres  = (u16*)(ws + 106 * MB);
  u16* Pb    = (u16*)(ws + 122 * MB);
  u16* tb    = Kb;   // FFN mid, K dead
  u16* ub    = Vb;   // FFN out, Vb dead

  // prep
  conv_x<<<(TOKS * DIMN) / 1024, 256, 0, stream>>>(x, xb);
  transpose_w5<<<dim3(32, 32, 5), dim3(32, 8), 0, stream>>>(
      Wq, Wk, Wv, W1, W2, WqkvT, W1T, W2T);

  // fused QKV projection: [8192,1024] @ [3072,1024]^T  (grid 1536 = 6 blk/CU)
  gemm_bt<3><<<dim3(64, 24), 256, 0, stream>>>(
      xb, WqkvT, Qb, Kb, Vb, bq, bk, bv,
      TOKS, 3 * DIMN, DIMN, DIMN, 0, 0, 0);

  // V -> V^T per batch (coalesced 32x32 tiles)
  transpose_v<<<dim3(32, 64, NBAT), dim3(32, 8), 0, stream>>>(Vb, VT);

  // scores (bf16 out), batched over grid.z
  gemm_bt<6><<<dim3(16, 16, NBAT), 256, 0, stream>>>(
      Qb, Kb, Sc, nullptr, nullptr, nullptr, nullptr, nullptr,
      SEQ, SEQ, DIMN, SEQ,
      (size_t)SEQ * DIMN, (size_t)SEQ * DIMN, (size_t)SEQ * SEQ);
  softmax_rows<<<TOKS, 256, 0, stream>>>(Sc, Pb);
  gemm_bt<6><<<dim3(16, 8, NBAT), 256, 0, stream>>>(
      Pb, VT, attn, nullptr, nullptr, nullptr, nullptr, nullptr,
      SEQ, DIMN, SEQ, DIMN,
      (size_t)SEQ * SEQ, (size_t)DIMN * SEQ, (size_t)SEQ * DIMN);

  // h = LN(LN(attn+x)+x) -> hres bf16 (serves GEMM A and final residual)
  ln1_fused<<<TOKS, 256, 0, stream>>>(attn, xb, g_at, b_at, g_ln, b_ln, hres);

  // FFN
  gemm_bt<4><<<dim3(64, 8), 256, 0, stream>>>(
      hres, W1T, tb, nullptr, nullptr, c1, nullptr, nullptr,
      TOKS, DIMN, DIMN, DIMN, 0, 0, 0);
  gemm_bt<4><<<dim3(64, 8), 256, 0, stream>>>(
      tb, W2T, ub, nullptr, nullptr, c2, nullptr, nullptr,
      TOKS, DIMN, DIMN, DIMN, 0, 0, 0);

  // out = LN(u + h)
  ln2_final<<<TOKS, 256, 0, stream>>>(ub, hres, g_ln, b_ln, out);
}

// Round 5
// 382.566 us; speedup vs baseline: 1.4969x; 1.0654x over previous
//
#include <hip/hip_runtime.h>
#include <cstdint>
#include <cstddef>

// Problem constants
#define DIMN 1024
#define SEQ  2048
#define NBAT 4
#define TOKS (NBAT * SEQ)   // 8192

typedef unsigned short u16;
typedef unsigned int   u32;

typedef __bf16 bf16x8 __attribute__((ext_vector_type(8)));
typedef float  f32x4  __attribute__((ext_vector_type(4)));

#define AS1 __attribute__((address_space(1)))
#define AS3 __attribute__((address_space(3)))

// ---- helpers ----------------------------------------------------------------

__device__ __forceinline__ u16 f2b(float f) {
  union { float f; u32 u; } v; v.f = f;
  u32 r = v.u + 0x7fffu + ((v.u >> 16) & 1u);   // round-to-nearest-even
  return (u16)(r >> 16);
}

__device__ __forceinline__ float b2f(u16 b) {
  union { u32 u; float f; } v; v.u = ((u32)b) << 16;
  return v.f;
}

__device__ __forceinline__ float gelu_exact(float v) {
  return 0.5f * v * (1.0f + erff(v * 0.70710678118654752f));
}

__device__ __forceinline__ void blk_sum2(float& a, float& b, float* sm) {
  #pragma unroll
  for (int o = 32; o >= 1; o >>= 1) {
    a += __shfl_xor(a, o, 64);
    b += __shfl_xor(b, o, 64);
  }
  int w = threadIdx.x >> 6;
  if ((threadIdx.x & 63) == 0) { sm[w] = a; sm[4 + w] = b; }
  __syncthreads();
  a = sm[0] + sm[1] + sm[2] + sm[3];
  b = sm[4] + sm[5] + sm[6] + sm[7];
  __syncthreads();
}

__device__ __forceinline__ float blk_max(float a, float* sm) {
  #pragma unroll
  for (int o = 32; o >= 1; o >>= 1) a = fmaxf(a, __shfl_xor(a, o, 64));
  int w = threadIdx.x >> 6;
  if ((threadIdx.x & 63) == 0) sm[w] = a;
  __syncthreads();
  float r = fmaxf(fmaxf(sm[0], sm[1]), fmaxf(sm[2], sm[3]));
  __syncthreads();
  return r;
}

__device__ __forceinline__ float blk_sum1(float a, float* sm) {
  #pragma unroll
  for (int o = 32; o >= 1; o >>= 1) a += __shfl_xor(a, o, 64);
  int w = threadIdx.x >> 6;
  if ((threadIdx.x & 63) == 0) sm[w] = a;
  __syncthreads();
  float r = sm[0] + sm[1] + sm[2] + sm[3];
  __syncthreads();
  return r;
}

// ---- prep kernels -----------------------------------------------------------

__global__ __launch_bounds__(256) void conv_x(const float* __restrict__ x,
                                              u16* __restrict__ xb) {
  size_t i = ((size_t)blockIdx.x * 256 + threadIdx.x) * 4;
  float4 v = *(const float4*)(x + i);
  uint2 o;
  o.x = (u32)f2b(v.x) | ((u32)f2b(v.y) << 16);
  o.y = (u32)f2b(v.z) | ((u32)f2b(v.w) << 16);
  *(uint2*)(xb + i) = o;
}

// All 5 weight transposes in one dispatch: W [K][N] f32 -> WT [N][K] bf16.
// Wq/Wk/Wv write into one contiguous [3072][1024] block (QKV merged B).
__global__ __launch_bounds__(256) void transpose_w5(
    const float* __restrict__ Wq, const float* __restrict__ Wk,
    const float* __restrict__ Wv, const float* __restrict__ W1,
    const float* __restrict__ W2,
    u16* __restrict__ Wqkv, u16* __restrict__ W1T, u16* __restrict__ W2T)
{
  const float* W; u16* T;
  switch (blockIdx.z) {
    case 0: W = Wq; T = Wqkv;                      break;
    case 1: W = Wk; T = Wqkv + 1 * DIMN * DIMN;    break;
    case 2: W = Wv; T = Wqkv + 2 * DIMN * DIMN;    break;
    case 3: W = W1; T = W1T;                       break;
    default: W = W2; T = W2T;                      break;
  }
  __shared__ float t[32][33];
  int tx = threadIdx.x, ty = threadIdx.y;
  int k0 = blockIdx.x * 32, n0 = blockIdx.y * 32;
  #pragma unroll
  for (int j = 0; j < 32; j += 8)
    t[ty + j][tx] = W[(size_t)(k0 + ty + j) * DIMN + n0 + tx];
  __syncthreads();
  #pragma unroll
  for (int j = 0; j < 32; j += 8)
    T[(size_t)(n0 + ty + j) * DIMN + k0 + tx] = f2b(t[tx][ty + j]);
}

// Vb[b][tok][d] bf16 -> VT[b][d][tok] bf16 (per-batch 2048x1024 transpose)
__global__ __launch_bounds__(256) void transpose_v(const u16* __restrict__ Vb,
                                                   u16* __restrict__ VT) {
  __shared__ u16 t[32][33];
  int tx = threadIdx.x, ty = threadIdx.y;
  int d0 = blockIdx.x * 32, t0 = blockIdx.y * 32;
  const u16* src = Vb + (size_t)blockIdx.z * SEQ * DIMN;
  u16*       dst = VT + (size_t)blockIdx.z * DIMN * SEQ;
  #pragma unroll
  for (int j = 0; j < 32; j += 8)
    t[ty + j][tx] = src[(size_t)(t0 + ty + j) * DIMN + d0 + tx];
  __syncthreads();
  #pragma unroll
  for (int j = 0; j < 32; j += 8)
    dst[(size_t)(d0 + ty + j) * SEQ + t0 + tx] = t[tx][ty + j];
}

// ---- MFMA GEMM: C[M,N] = A[M,K] * B^T  (B given as [N][K]) ------------------
// 128x128 tile, BK=64, 256 threads = 4 waves, wave tile 64x64 (4x4 of 16x16x32).
// Staging via global_load_lds width=16; XOR chunk swizzle (0 bank conflicts).
// SWZ=1 (tall GEMMs, gridDim.x%8==0): HW round-robins block id -> XCD (id%8);
//   give each XCD a bm-band of gridDim.x/8 rows (A band resident in 4MiB L2),
//   traverse n-major (each B tile fetched once per XCD).
//   Round-4 lesson: the m-major/n-band orientation streamed ALL of A through
//   every XCD -> 199.7 MB FETCH on QKV (9x ideal).
// SWZ=0: natural order (squat attention GEMMs; banding pessimizes them).
// EPI: 3 = QKV routed (+bias per 1024-segment, bf16 to Cb/Cb2/Cb3)
//      4 = +bias, GELU, bf16
//      6 = plain bf16
template <int EPI, int SWZ>
__global__ __launch_bounds__(256) void gemm_bt(
    const u16* __restrict__ A, const u16* __restrict__ Bm,
    u16* __restrict__ Cb, u16* __restrict__ Cb2, u16* __restrict__ Cb3,
    const float* __restrict__ bias, const float* __restrict__ bias2,
    const float* __restrict__ bias3,
    int M, int N, int K, int ldc,
    size_t sA, size_t sB, size_t sC)
{
  __shared__ u16 As[128 * 64];   // 16 KiB
  __shared__ u16 Bs[128 * 64];

  const int tid = threadIdx.x;

  int bm0, bn0;
  if (SWZ == 1) {
    const int id   = blockIdx.y * gridDim.x + blockIdx.x;
    const int xcd  = id & 7;
    const int idx  = id >> 3;
    const int band = gridDim.x >> 3;          // bm rows per XCD
    const int bm_l = idx % band;
    const int bn   = idx / band;
    bm0 = (xcd * band + bm_l) * 128;
    bn0 = bn * 128;
  } else {
    bm0 = blockIdx.x * 128;
    bn0 = blockIdx.y * 128;
  }

  A  += (size_t)blockIdx.z * sA;
  Bm += (size_t)blockIdx.z * sB;
  const int wave = tid >> 6, lane = tid & 63;
  const int wm   = (wave >> 1) * 64, wn = (wave & 1) * 64;
  const int l16  = lane & 15, quad = lane >> 4;

  f32x4 acc[4][4] = {};

  for (int k0 = 0; k0 < K; k0 += 64) {
    #pragma unroll
    for (int j = 0; j < 4; ++j) {
      const int c  = wave * 256 + j * 64 + lane;
      const int r  = c >> 3;
      const int cg = (c & 7) ^ (r & 7);
      const u16* gA = A  + (size_t)(bm0 + r) * K + k0 + cg * 8;
      const u16* gB = Bm + (size_t)(bn0 + r) * K + k0 + cg * 8;
      u16* lA = As + (wave * 4 + j) * 512;   // wave-uniform base, +lane*16B in HW
      u16* lB = Bs + (wave * 4 + j) * 512;
      __builtin_amdgcn_global_load_lds((const AS1 void*)gA, (AS3 void*)lA, 16, 0, 0);
      __builtin_amdgcn_global_load_lds((const AS1 void*)gB, (AS3 void*)lB, 16, 0, 0);
    }
    __syncthreads();

    #pragma unroll
    for (int kk = 0; kk < 64; kk += 32) {
      const int kc = kk >> 3;
      const int sw = l16 & 7;
      bf16x8 af[4], bfr[4];
      #pragma unroll
      for (int t = 0; t < 4; ++t) {
        const int row = wm + t * 16 + l16;
        af[t] = *(const bf16x8*)(&As[row * 64 + (((kc + quad) ^ sw) << 3)]);
      }
      #pragma unroll
      for (int t = 0; t < 4; ++t) {
        const int row = wn + t * 16 + l16;
        bfr[t] = *(const bf16x8*)(&Bs[row * 64 + (((kc + quad) ^ sw) << 3)]);
      }
      #pragma unroll
      for (int mt = 0; mt < 4; ++mt)
        #pragma unroll
        for (int nt = 0; nt < 4; ++nt)
          acc[mt][nt] = __builtin_amdgcn_mfma_f32_16x16x32_bf16(
              af[mt], bfr[nt], acc[mt][nt], 0, 0, 0);
    }
    __syncthreads();
  }

  u16* Cbz = Cb + (size_t)blockIdx.z * sC;

  // epilogue: C/D layout col = lane&15, row = quad*4 + reg
  #pragma unroll
  for (int mt = 0; mt < 4; ++mt) {
    int grow0 = bm0 + wm + mt * 16 + quad * 4;
    #pragma unroll
    for (int nt = 0; nt < 4; ++nt) {
      int gcol = bn0 + wn + nt * 16 + l16;
      if (EPI == 3) {
        const int seg = gcol >> 10;
        const int col = gcol & 1023;
        const float* bp = (seg == 0) ? bias : (seg == 1) ? bias2 : bias3;
        u16*         cp = (seg == 0) ? Cb   : (seg == 1) ? Cb2   : Cb3;
        float bv = bp[col];
        #pragma unroll
        for (int r = 0; r < 4; ++r)
          cp[(size_t)(grow0 + r) * ldc + col] = f2b(acc[mt][nt][r] + bv);
      } else if (EPI == 4) {
        float bv = bias[gcol];
        #pragma unroll
        for (int r = 0; r < 4; ++r)
          Cbz[(size_t)(grow0 + r) * ldc + gcol] =
              f2b(gelu_exact(acc[mt][nt][r] + bv));
      } else {  // 6
        #pragma unroll
        for (int r = 0; r < 4; ++r)
          Cbz[(size_t)(grow0 + r) * ldc + gcol] = f2b(acc[mt][nt][r]);
      }
    }
  }
}

// ---- softmax over rows of 2048 (bf16 in), scale 1/8, write bf16 P -----------
__global__ __launch_bounds__(256) void softmax_rows(const u16* __restrict__ Sc,
                                                    u16* __restrict__ P) {
  __shared__ float sm[8];
  int row = blockIdx.x, t = threadIdx.x;
  const u16* s = Sc + (size_t)row * SEQ;
  uint4 raw = *(const uint4*)(s + t * 8);
  float v[8];
  #pragma unroll
  for (int m = 0; m < 4; ++m) {
    u32 w = ((const u32*)&raw)[m];
    v[2 * m]     = b2f((u16)(w & 0xffff)) * 0.125f;
    v[2 * m + 1] = b2f((u16)(w >> 16)) * 0.125f;
  }
  float mx = -1e30f;
  #pragma unroll
  for (int i = 0; i < 8; ++i) mx = fmaxf(mx, v[i]);
  mx = blk_max(mx, sm);
  float sum = 0.0f;
  #pragma unroll
  for (int i = 0; i < 8; ++i) { v[i] = __expf(v[i] - mx); sum += v[i]; }
  sum = blk_sum1(sum, sm);
  float inv = 1.0f / sum;
  uint4 o;
  #pragma unroll
  for (int m = 0; m < 4; ++m)
    ((u32*)&o)[m] = (u32)f2b(v[2 * m] * inv) | ((u32)f2b(v[2 * m + 1] * inv) << 16);
  *(uint4*)(P + (size_t)row * SEQ + t * 8) = o;
}

// ---- h = LN( LN(attn+x)*g_at+b_at + x )*g_ln+b_ln  -> hres bf16 -------------
__global__ __launch_bounds__(256) void ln1_fused(
    const u16* __restrict__ attn, const u16* __restrict__ xb,
    const float* __restrict__ g_at, const float* __restrict__ b_at,
    const float* __restrict__ g_ln, const float* __restrict__ b_ln,
    u16* __restrict__ hres)
{
  __shared__ float sm[8];
  int row = blockIdx.x, t = threadIdx.x;
  size_t base = (size_t)row * DIMN;
  uint2 ar = *(const uint2*)(attn + base + t * 4);
  uint2 xr4 = *(const uint2*)(xb + base + t * 4);
  float y[4], xr[4];
  float s = 0.0f, s2 = 0.0f;
  #pragma unroll
  for (int i = 0; i < 4; ++i) {
    u32 aw = ((const u32*)&ar)[i >> 1];
    u32 xw = ((const u32*)&xr4)[i >> 1];
    float av = b2f((u16)((i & 1) ? (aw >> 16) : (aw & 0xffff)));
    xr[i]    = b2f((u16)((i & 1) ? (xw >> 16) : (xw & 0xffff)));
    y[i] = av + xr[i];
    s += y[i]; s2 += y[i] * y[i];
  }
  blk_sum2(s, s2, sm);
  float m  = s * (1.0f / DIMN);
  float rs = rsqrtf(s2 * (1.0f / DIMN) - m * m + 1e-5f);
  float z[4];
  s = 0.0f; s2 = 0.0f;
  #pragma unroll
  for (int i = 0; i < 4; ++i) {
    int c = t * 4 + i;
    float at = (y[i] - m) * rs * g_at[c] + b_at[c];
    z[i] = at + xr[i];
    s += z[i]; s2 += z[i] * z[i];
  }
  blk_sum2(s, s2, sm);
  float m2  = s * (1.0f / DIMN);
  float rs2 = rsqrtf(s2 * (1.0f / DIMN) - m2 * m2 + 1e-5f);
  uint2 o;
  #pragma unroll
  for (int i = 0; i < 2; ++i) {
    int c = t * 4 + 2 * i;
    float h0 = (z[2 * i]     - m2) * rs2 * g_ln[c]     + b_ln[c];
    float h1 = (z[2 * i + 1] - m2) * rs2 * g_ln[c + 1] + b_ln[c + 1];
    ((u32*)&o)[i] = (u32)f2b(h0) | ((u32)f2b(h1) << 16);
  }
  *(uint2*)(hres + base + t * 4) = o;
}

// ---- out = LN(u + hres)*g_ln + b_ln  (bf16 in, f32 out) ---------------------
__global__ __launch_bounds__(256) void ln2_final(
    const u16* __restrict__ u, const u16* __restrict__ hres,
    const float* __restrict__ g, const float* __restrict__ bb,
    float* __restrict__ out)
{
  __shared__ float sm[8];
  int row = blockIdx.x, t = threadIdx.x;
  size_t base = (size_t)row * DIMN;
  uint2 ur = *(const uint2*)(u + base + t * 4);
  uint2 hr = *(const uint2*)(hres + base + t * 4);
  float y[4];
  float s = 0.0f, s2 = 0.0f;
  #pragma unroll
  for (int i = 0; i < 4; ++i) {
    u32 uw = ((const u32*)&ur)[i >> 1];
    u32 hw = ((const u32*)&hr)[i >> 1];
    float uv = b2f((u16)((i & 1) ? (uw >> 16) : (uw & 0xffff)));
    float hv = b2f((u16)((i & 1) ? (hw >> 16) : (hw & 0xffff)));
    y[i] = uv + hv;
    s += y[i]; s2 += y[i] * y[i];
  }
  blk_sum2(s, s2, sm);
  float m  = s * (1.0f / DIMN);
  float rs = rsqrtf(s2 * (1.0f / DIMN) - m * m + 1e-5f);
  float4 o;
  o.x = (y[0] - m) * rs * g[t * 4 + 0] + bb[t * 4 + 0];
  o.y = (y[1] - m) * rs * g[t * 4 + 1] + bb[t * 4 + 1];
  o.z = (y[2] - m) * rs * g[t * 4 + 2] + bb[t * 4 + 2];
  o.w = (y[3] - m) * rs * g[t * 4 + 3] + bb[t * 4 + 3];
  *(float4*)(out + base + t * 4) = o;
}

// ---- launch -----------------------------------------------------------------

extern "C" void kernel_launch(void* const* d_in, const int* in_sizes, int n_in,
                              void* d_out, int out_size, void* d_ws, size_t ws_size,
                              hipStream_t stream)
{
  const float* x    = (const float*)d_in[0];
  const float* Wq   = (const float*)d_in[1];
  const float* bq   = (const float*)d_in[2];
  const float* Wk   = (const float*)d_in[3];
  const float* bk   = (const float*)d_in[4];
  const float* Wv   = (const float*)d_in[5];
  const float* bv   = (const float*)d_in[6];
  const float* g_at = (const float*)d_in[7];
  const float* b_at = (const float*)d_in[8];
  const float* g_ln = (const float*)d_in[9];
  const float* b_ln = (const float*)d_in[10];
  const float* W1   = (const float*)d_in[11];
  const float* c1   = (const float*)d_in[12];
  const float* W2   = (const float*)d_in[13];
  const float* c2   = (const float*)d_in[14];
  float* out = (float*)d_out;

  // workspace layout (1 MiB units), peak 154 MiB:
  //   0..16  xb      (alive through ln1)
  //  16..18  W1T   18..20 W2T   20..26 WqkvT [3072][1024]
  //  26..42  Qb      (dead after scores)
  //  42..58  Kb      (dead after scores; tb alias for FFN mid)
  //  58..74  Vb      (dead after transpose_v; ub alias for FFN out)
  //  74..90  VT
  //  90..122 Sc bf16 (dead after softmax; attn 90..106, hres 106..122 alias)
  // 122..154 Pb bf16
  char* ws = (char*)d_ws;
  const size_t MB = 1u << 20;
  u16* xb    = (u16*)(ws + 0 * MB);
  u16* W1T   = (u16*)(ws + 16 * MB);
  u16* W2T   = (u16*)(ws + 18 * MB);
  u16* WqkvT = (u16*)(ws + 20 * MB);
  u16* Qb    = (u16*)(ws + 26 * MB);
  u16* Kb    = (u16*)(ws + 42 * MB);
  u16* Vb    = (u16*)(ws + 58 * MB);
  u16* VT    = (u16*)(ws + 74 * MB);
  u16* Sc    = (u16*)(ws + 90 * MB);
  u16* attn  = (u16*)(ws + 90 * MB);
  u16* hres  = (u16*)(ws + 106 * MB);
  u16* Pb    = (u16*)(ws + 122 * MB);
  u16* tb    = Kb;   // FFN mid, K dead
  u16* ub    = Vb;   // FFN out, Vb dead

  // prep
  conv_x<<<(TOKS * DIMN) / 1024, 256, 0, stream>>>(x, xb);
  transpose_w5<<<dim3(32, 32, 5), dim3(32, 8), 0, stream>>>(
      Wq, Wk, Wv, W1, W2, WqkvT, W1T, W2T);

  // fused QKV projection: [8192,1024] @ [3072,1024]^T, bm-band swizzle
  gemm_bt<3, 1><<<dim3(64, 24), 256, 0, stream>>>(
      xb, WqkvT, Qb, Kb, Vb, bq, bk, bv,
      TOKS, 3 * DIMN, DIMN, DIMN, 0, 0, 0);

  // V -> V^T per batch (coalesced 32x32 tiles)
  transpose_v<<<dim3(32, 64, NBAT), dim3(32, 8), 0, stream>>>(Vb, VT);

  // scores (bf16 out), batched over grid.z, natural order
  gemm_bt<6, 0><<<dim3(16, 16, NBAT), 256, 0, stream>>>(
      Qb, Kb, Sc, nullptr, nullptr, nullptr, nullptr, nullptr,
      SEQ, SEQ, DIMN, SEQ,
      (size_t)SEQ * DIMN, (size_t)SEQ * DIMN, (size_t)SEQ * SEQ);
  softmax_rows<<<TOKS, 256, 0, stream>>>(Sc, Pb);
  gemm_bt<6, 0><<<dim3(16, 8, NBAT), 256, 0, stream>>>(
      Pb, VT, attn, nullptr, nullptr, nullptr, nullptr, nullptr,
      SEQ, DIMN, SEQ, DIMN,
      (size_t)SEQ * SEQ, (size_t)DIMN * SEQ, (size_t)SEQ * DIMN);

  // h = LN(LN(attn+x)+x) -> hres bf16 (serves GEMM A and final residual)
  ln1_fused<<<TOKS, 256, 0, stream>>>(attn, xb, g_at, b_at, g_ln, b_ln, hres);

  // FFN (bm-band swizzle)
  gemm_bt<4, 1><<<dim3(64, 8), 256, 0, stream>>>(
      hres, W1T, tb, nullptr, nullptr, c1, nullptr, nullptr,
      TOKS, DIMN, DIMN, DIMN, 0, 0, 0);
  gemm_bt<4, 1><<<dim3(64, 8), 256, 0, stream>>>(
      tb, W2T, ub, nullptr, nullptr, c2, nullptr, nullptr,
      TOKS, DIMN, DIMN, DIMN, 0, 0, 0);

  // out = LN(u + h)
  ln2_final<<<TOKS, 256, 0, stream>>>(ub, hres, g_ln, b_ln, out);
}